// Round 1
// baseline (324.209 us; speedup 1.0000x reference)
//
#include <hip/hip_runtime.h>
#include <math.h>

#define T_ 16
#define B_ 1024
#define F_ 512
#define H_ 128
#define D_ 8
#define C_ 100
#define L_ 512

// ---------------------------------------------------------------------------
// k1: h[t][b][j] = relu(feat[b,:] @ W1[t,:,j] + b1[t][j])
// grid (B/32, T), block 256. C-tile 32(b) x 128(h), K-tile 32.
// ---------------------------------------------------------------------------
__global__ __launch_bounds__(256) void k1_gemm_h(
    const float* __restrict__ feat, const float* __restrict__ W1,
    const float* __restrict__ b1, float* __restrict__ h_out) {
  __shared__ float feat_s[32][33];   // +1 pad: conflict-free row reads
  __shared__ float w_s[32][128];
  const int t  = blockIdx.y;
  const int b0 = blockIdx.x * 32;
  const int tid = threadIdx.x;
  const int tx = tid % 32;           // h: tx + 32*i
  const int ty = tid / 32;           // b: ty*4 + j
  float acc[4][4] = {};
  const float* W1t = W1 + (size_t)t * F_ * H_;

  for (int k0 = 0; k0 < F_; k0 += 32) {
    {  // feat tile 32x32, one float4 per thread
      int row = tid / 8;
      int cg  = (tid % 8) * 4;
      float4 v = *(const float4*)(feat + (size_t)(b0 + row) * F_ + k0 + cg);
      feat_s[row][cg + 0] = v.x; feat_s[row][cg + 1] = v.y;
      feat_s[row][cg + 2] = v.z; feat_s[row][cg + 3] = v.w;
    }
    {  // W1 tile 32x128, four float4 per thread
      int hc = (tid % 32) * 4;
      int kb = tid / 32;
#pragma unroll
      for (int r = 0; r < 4; ++r) {
        int k = kb + r * 8;
        *(float4*)&w_s[k][hc] = *(const float4*)(W1t + (size_t)(k0 + k) * H_ + hc);
      }
    }
    __syncthreads();
#pragma unroll
    for (int kk = 0; kk < 32; ++kk) {
      float a0 = feat_s[ty * 4 + 0][kk];
      float a1 = feat_s[ty * 4 + 1][kk];
      float a2 = feat_s[ty * 4 + 2][kk];
      float a3 = feat_s[ty * 4 + 3][kk];
      float w0 = w_s[kk][tx];
      float w1 = w_s[kk][tx + 32];
      float w2 = w_s[kk][tx + 64];
      float w3 = w_s[kk][tx + 96];
      acc[0][0] += a0 * w0; acc[0][1] += a0 * w1; acc[0][2] += a0 * w2; acc[0][3] += a0 * w3;
      acc[1][0] += a1 * w0; acc[1][1] += a1 * w1; acc[1][2] += a1 * w2; acc[1][3] += a1 * w3;
      acc[2][0] += a2 * w0; acc[2][1] += a2 * w1; acc[2][2] += a2 * w2; acc[2][3] += a2 * w3;
      acc[3][0] += a3 * w0; acc[3][1] += a3 * w1; acc[3][2] += a3 * w2; acc[3][3] += a3 * w3;
    }
    __syncthreads();
  }
#pragma unroll
  for (int j = 0; j < 4; ++j) {
    int b = b0 + ty * 4 + j;
#pragma unroll
    for (int i = 0; i < 4; ++i) {
      int hh = tx + 32 * i;
      float v = acc[j][i] + b1[t * H_ + hh];
      h_out[((size_t)t * B_ + b) * H_ + hh] = v > 0.0f ? v : 0.0f;
    }
  }
}

// ---------------------------------------------------------------------------
// k2: fused  p = sigmoid(h @ W2 + b2)  (kept in LDS only)  +  routing product
//     mu[t][b][l] = prod_d ( side(d,l) ? 1-p[node(d,l)] : p[node(d,l)] )
// grid (B/8, T), block 256. Each block: one tree t, 8 batch rows.
// ---------------------------------------------------------------------------
__global__ __launch_bounds__(256) void k2_p_mu(
    const float* __restrict__ h_in, const float* __restrict__ W2,
    const float* __restrict__ b2, float* __restrict__ mu) {
  __shared__ float h_s[8][128];
  __shared__ float p_s[8][512];
  const int t  = blockIdx.y;
  const int b0 = blockIdx.x * 8;
  const int tid = threadIdx.x;
  {  // load 8x128 h rows
    int bb  = tid / 32;
    int idx = (tid % 32) * 4;
    *(float4*)&h_s[bb][idx] =
        *(const float4*)(h_in + ((size_t)t * B_ + b0 + bb) * H_ + idx);
  }
  __syncthreads();

  const float* W2t = W2 + (size_t)t * H_ * L_;
  float acc[8][2] = {};
#pragma unroll 4
  for (int k = 0; k < H_; ++k) {
    float w0 = W2t[(size_t)k * L_ + tid];
    float w1 = W2t[(size_t)k * L_ + tid + 256];
#pragma unroll
    for (int bb = 0; bb < 8; ++bb) {
      float hv = h_s[bb][k];
      acc[bb][0] += hv * w0;
      acc[bb][1] += hv * w1;
    }
  }
  float bias0 = b2[t * L_ + tid];
  float bias1 = b2[t * L_ + tid + 256];
#pragma unroll
  for (int bb = 0; bb < 8; ++bb) {
    float x0 = acc[bb][0] + bias0;
    float x1 = acc[bb][1] + bias1;
    p_s[bb][tid]       = 1.0f / (1.0f + __expf(-x0));
    p_s[bb][tid + 256] = 1.0f / (1.0f + __expf(-x1));
  }
  __syncthreads();

#pragma unroll
  for (int li = 0; li < 2; ++li) {
    int l = tid + li * 256;
#pragma unroll
    for (int bb = 0; bb < 8; ++bb) {
      float m = 1.0f;
#pragma unroll
      for (int d = 0; d <= D_; ++d) {
        int node = (1 << d) - 1 + (l >> (D_ + 1 - d));
        int side = (l >> (D_ - d)) & 1;
        float sel = p_s[bb][node];
        m *= side ? (1.0f - sel) : sel;
      }
      mu[((size_t)t * B_ + b0 + bb) * L_ + l] = m;
    }
  }
}

// ---------------------------------------------------------------------------
// k4: leaf_p[t][l][:] = softmax(pi[t][l][:])  — one wave per row of C=100
// grid T*L/4, block 256 (4 waves)
// ---------------------------------------------------------------------------
__global__ __launch_bounds__(256) void k4_softmax(
    const float* __restrict__ pi, float* __restrict__ leaf_p) {
  int row  = blockIdx.x * 4 + (threadIdx.x >> 6);
  int lane = threadIdx.x & 63;
  const float* x = pi + (size_t)row * C_;
  float v0 = (lane < C_) ? x[lane] : -1e30f;
  float v1 = (lane + 64 < C_) ? x[lane + 64] : -1e30f;
  float m = fmaxf(v0, v1);
#pragma unroll
  for (int off = 32; off; off >>= 1) m = fmaxf(m, __shfl_xor(m, off, 64));
  float e0 = __expf(v0 - m);
  float e1 = (lane + 64 < C_) ? __expf(v1 - m) : 0.0f;
  float s = e0 + e1;
#pragma unroll
  for (int off = 32; off; off >>= 1) s += __shfl_xor(s, off, 64);
  float inv = 1.0f / s;
  if (lane < C_)      leaf_p[(size_t)row * C_ + lane]      = e0 * inv;
  if (lane + 64 < C_) leaf_p[(size_t)row * C_ + lane + 64] = e1 * inv;
}

// ---------------------------------------------------------------------------
// k5: part[tz][b][c] = sum_{t in tz-group} sum_l mu[t][b][l] * leaf_p[t][l][c]
// grid (B/8, 4), block 128. mu staged in LDS, threads = c (100 active).
// ---------------------------------------------------------------------------
__global__ __launch_bounds__(128) void k5_acc(
    const float* __restrict__ mu, const float* __restrict__ leaf_p,
    float* __restrict__ part) {
  __shared__ float mu_s[8 * 512];
  const int b0  = blockIdx.x * 8;
  const int tz  = blockIdx.y;  // t-group of 4
  const int tid = threadIdx.x;
  float acc[8] = {};
  for (int ti = 0; ti < 4; ++ti) {
    int t = tz * 4 + ti;
    __syncthreads();
    const float* src = mu + ((size_t)t * B_ + b0) * L_;   // 8 rows contiguous
#pragma unroll
    for (int chunk = 0; chunk < 8; ++chunk)
      *(float4*)&mu_s[chunk * 512 + tid * 4] =
          *(const float4*)(src + chunk * 512 + tid * 4);
    __syncthreads();
    if (tid < C_) {
      const float* lp = leaf_p + (size_t)t * L_ * C_ + tid;
      for (int l = 0; l < L_; ++l) {
        float v = lp[(size_t)l * C_];
#pragma unroll
        for (int bb = 0; bb < 8; ++bb) acc[bb] += mu_s[bb * 512 + l] * v;
      }
    }
  }
  if (tid < C_) {
#pragma unroll
    for (int bb = 0; bb < 8; ++bb)
      part[((size_t)tz * B_ + b0 + bb) * C_ + tid] = acc[bb];
  }
}

// ---------------------------------------------------------------------------
// k6: out[b][c] = log( (sum_tz part[tz][b][c]) / (L*T) )
// ---------------------------------------------------------------------------
__global__ __launch_bounds__(256) void k6_log(
    const float* __restrict__ part, float* __restrict__ out) {
  int i = blockIdx.x * 256 + threadIdx.x;
  if (i < B_ * C_) {
    float s = part[i] + part[B_ * C_ + i] + part[2 * B_ * C_ + i] +
              part[3 * B_ * C_ + i];
    out[i] = logf(s * (1.0f / (L_ * T_)));
  }
}

extern "C" void kernel_launch(void* const* d_in, const int* in_sizes, int n_in,
                              void* d_out, int out_size, void* d_ws,
                              size_t ws_size, hipStream_t stream) {
  const float* feat = (const float*)d_in[0];
  const float* W1   = (const float*)d_in[1];
  const float* b1   = (const float*)d_in[2];
  const float* W2   = (const float*)d_in[3];
  const float* b2   = (const float*)d_in[4];
  const float* pi   = (const float*)d_in[5];
  float* out = (float*)d_out;

  char* ws = (char*)d_ws;
  float* h_buf    = (float*)(ws);                                   // 8 MB
  float* mu_buf   = (float*)(ws + (size_t)8 * 1024 * 1024);         // 32 MB
  float* leaf_buf = (float*)(ws + (size_t)40 * 1024 * 1024);        // 3.28 MB
  float* part_buf = (float*)(ws + (size_t)44 * 1024 * 1024);        // 1.6 MB

  k1_gemm_h<<<dim3(B_ / 32, T_), 256, 0, stream>>>(feat, W1, b1, h_buf);
  k2_p_mu<<<dim3(B_ / 8, T_), 256, 0, stream>>>(h_buf, W2, b2, mu_buf);
  k4_softmax<<<(T_ * L_) / 4, 256, 0, stream>>>(pi, leaf_buf);
  k5_acc<<<dim3(B_ / 8, 4), 128, 0, stream>>>(mu_buf, leaf_buf, part_buf);
  k6_log<<<(B_ * C_ + 255) / 256, 256, 0, stream>>>(part_buf, out);
}

// Round 3
// 189.275 us; speedup vs baseline: 1.7129x; 1.7129x over previous
//
#include <hip/hip_runtime.h>
#include <hip/hip_bf16.h>
#include <math.h>

#define T_ 16
#define B_ 1024
#define F_ 512
#define H_ 128
#define D_ 8
#define C_ 100
#define L_ 512
#define CP_ 112   // C padded to multiple of 16 for MFMA N

typedef __attribute__((ext_vector_type(8))) short bf16x8_t;
typedef __attribute__((ext_vector_type(4))) short bf16x4_t;
typedef __attribute__((ext_vector_type(4))) float f32x4_t;

// ---------------------------------------------------------------------------
// k1: h[t][b][j] = relu(feat[b,:] @ W1[t,:,j] + b1[t][j])   (unchanged)
// ---------------------------------------------------------------------------
__global__ __launch_bounds__(256) void k1_gemm_h(
    const float* __restrict__ feat, const float* __restrict__ W1,
    const float* __restrict__ b1, float* __restrict__ h_out) {
  __shared__ float feat_s[32][33];
  __shared__ float w_s[32][128];
  const int t  = blockIdx.y;
  const int b0 = blockIdx.x * 32;
  const int tid = threadIdx.x;
  const int tx = tid % 32;
  const int ty = tid / 32;
  float acc[4][4] = {};
  const float* W1t = W1 + (size_t)t * F_ * H_;

  for (int k0 = 0; k0 < F_; k0 += 32) {
    {
      int row = tid / 8;
      int cg  = (tid % 8) * 4;
      float4 v = *(const float4*)(feat + (size_t)(b0 + row) * F_ + k0 + cg);
      feat_s[row][cg + 0] = v.x; feat_s[row][cg + 1] = v.y;
      feat_s[row][cg + 2] = v.z; feat_s[row][cg + 3] = v.w;
    }
    {
      int hc = (tid % 32) * 4;
      int kb = tid / 32;
#pragma unroll
      for (int r = 0; r < 4; ++r) {
        int k = kb + r * 8;
        *(float4*)&w_s[k][hc] = *(const float4*)(W1t + (size_t)(k0 + k) * H_ + hc);
      }
    }
    __syncthreads();
#pragma unroll
    for (int kk = 0; kk < 32; ++kk) {
      float a0 = feat_s[ty * 4 + 0][kk];
      float a1 = feat_s[ty * 4 + 1][kk];
      float a2 = feat_s[ty * 4 + 2][kk];
      float a3 = feat_s[ty * 4 + 3][kk];
      float w0 = w_s[kk][tx];
      float w1 = w_s[kk][tx + 32];
      float w2 = w_s[kk][tx + 64];
      float w3 = w_s[kk][tx + 96];
      acc[0][0] += a0 * w0; acc[0][1] += a0 * w1; acc[0][2] += a0 * w2; acc[0][3] += a0 * w3;
      acc[1][0] += a1 * w0; acc[1][1] += a1 * w1; acc[1][2] += a1 * w2; acc[1][3] += a1 * w3;
      acc[2][0] += a2 * w0; acc[2][1] += a2 * w1; acc[2][2] += a2 * w2; acc[2][3] += a2 * w3;
      acc[3][0] += a3 * w0; acc[3][1] += a3 * w1; acc[3][2] += a3 * w2; acc[3][3] += a3 * w3;
    }
    __syncthreads();
  }
#pragma unroll
  for (int j = 0; j < 4; ++j) {
    int b = b0 + ty * 4 + j;
#pragma unroll
    for (int i = 0; i < 4; ++i) {
      int hh = tx + 32 * i;
      float v = acc[j][i] + b1[t * H_ + hh];
      h_out[((size_t)t * B_ + b) * H_ + hh] = v > 0.0f ? v : 0.0f;
    }
  }
}

// ---------------------------------------------------------------------------
// k2: fused p = sigmoid(h @ W2 + b2) (LDS only) + routing product
//     writes mu as bf16 (halves write traffic, enables MFMA in k5)
// ---------------------------------------------------------------------------
__global__ __launch_bounds__(256) void k2_p_mu(
    const float* __restrict__ h_in, const float* __restrict__ W2,
    const float* __restrict__ b2, __hip_bfloat16* __restrict__ mu) {
  __shared__ float h_s[8][128];
  __shared__ float p_s[8][512];
  const int t  = blockIdx.y;
  const int b0 = blockIdx.x * 8;
  const int tid = threadIdx.x;
  {
    int bb  = tid / 32;
    int idx = (tid % 32) * 4;
    *(float4*)&h_s[bb][idx] =
        *(const float4*)(h_in + ((size_t)t * B_ + b0 + bb) * H_ + idx);
  }
  __syncthreads();

  const float* W2t = W2 + (size_t)t * H_ * L_;
  float acc[8][2] = {};
#pragma unroll 4
  for (int k = 0; k < H_; ++k) {
    float w0 = W2t[(size_t)k * L_ + tid];
    float w1 = W2t[(size_t)k * L_ + tid + 256];
#pragma unroll
    for (int bb = 0; bb < 8; ++bb) {
      float hv = h_s[bb][k];
      acc[bb][0] += hv * w0;
      acc[bb][1] += hv * w1;
    }
  }
  float bias0 = b2[t * L_ + tid];
  float bias1 = b2[t * L_ + tid + 256];
#pragma unroll
  for (int bb = 0; bb < 8; ++bb) {
    float x0 = acc[bb][0] + bias0;
    float x1 = acc[bb][1] + bias1;
    p_s[bb][tid]       = 1.0f / (1.0f + __expf(-x0));
    p_s[bb][tid + 256] = 1.0f / (1.0f + __expf(-x1));
  }
  __syncthreads();

#pragma unroll
  for (int li = 0; li < 2; ++li) {
    int l = tid + li * 256;
#pragma unroll
    for (int bb = 0; bb < 8; ++bb) {
      float m = 1.0f;
#pragma unroll
      for (int d = 0; d <= D_; ++d) {
        int node = (1 << d) - 1 + (l >> (D_ + 1 - d));
        int side = (l >> (D_ - d)) & 1;
        float sel = p_s[bb][node];
        m *= side ? (1.0f - sel) : sel;
      }
      mu[((size_t)t * B_ + b0 + bb) * L_ + l] = __float2bfloat16(m);
    }
  }
}

// ---------------------------------------------------------------------------
// k4: leaf_p[t][l][:] = softmax(pi[t][l][:]) → bf16, padded to CP_=112 cols
// ---------------------------------------------------------------------------
__global__ __launch_bounds__(256) void k4_softmax(
    const float* __restrict__ pi, __hip_bfloat16* __restrict__ lp) {
  int row  = blockIdx.x * 4 + (threadIdx.x >> 6);
  int lane = threadIdx.x & 63;
  const float* x = pi + (size_t)row * C_;
  float v0 = (lane < C_) ? x[lane] : -1e30f;
  float v1 = (lane + 64 < C_) ? x[lane + 64] : -1e30f;
  float m = fmaxf(v0, v1);
#pragma unroll
  for (int off = 32; off; off >>= 1) m = fmaxf(m, __shfl_xor(m, off, 64));
  float e0 = __expf(v0 - m);
  float e1 = (lane + 64 < C_) ? __expf(v1 - m) : 0.0f;
  float s = e0 + e1;
#pragma unroll
  for (int off = 32; off; off >>= 1) s += __shfl_xor(s, off, 64);
  float inv = 1.0f / s;
  size_t base = (size_t)row * CP_;
  if (lane < C_) lp[base + lane] = __float2bfloat16(e0 * inv);
  int c2 = lane + 64;
  if (c2 < CP_) lp[base + c2] = __float2bfloat16(c2 < C_ ? e1 * inv : 0.0f);
}

// ---------------------------------------------------------------------------
// k5: MFMA mix:  part[t][b][c] = sum_l mu[t][b][l] * lp[t][l][c]
// grid (B/64=16, T=16), block 256 (4 waves, one 16-row m-tile each).
// A (mu, bf16) direct from global; B (lp) transposed into LDS per 64-k chunk.
// LDS pitch 68 ushorts: 8B-aligned dual-b64 frag loads, conflict-free.
// ---------------------------------------------------------------------------
__global__ __launch_bounds__(256) void k5_mfma(
    const ushort* __restrict__ mu, const ushort* __restrict__ lp,
    float* __restrict__ part) {
  __shared__ ushort bT[CP_ * 68];   // [c][k-chunk 64], pitch 68
  const int t   = blockIdx.y;
  const int m0  = blockIdx.x * 64;
  const int tid = threadIdx.x;
  const int wave = tid >> 6, lane = tid & 63;
  const int quad = lane >> 4;
  const int n    = lane & 15;
  const int mrow = m0 + wave * 16 + n;   // A-operand: m = lane&15

  f32x4_t acc[7];
#pragma unroll
  for (int i = 0; i < 7; ++i) acc[i] = (f32x4_t){0.f, 0.f, 0.f, 0.f};

  const ushort* muRow = mu + ((size_t)t * B_ + mrow) * L_;
  const ushort* lp_t  = lp + (size_t)t * L_ * CP_;

  for (int k0 = 0; k0 < L_; k0 += 64) {
    __syncthreads();
    // stage lp[k0..k0+64][0..112] transposed: bT[c][kk]
#pragma unroll
    for (int i = 0; i < 28; ++i) {
      int e  = i * 256 + tid;       // 28*256 = 7168 = 64*112, coalesced reads
      int kk = e / CP_;
      int c  = e - kk * CP_;
      bT[c * 68 + kk] = lp_t[(size_t)(k0 + kk) * CP_ + c];
    }
    __syncthreads();
#pragma unroll
    for (int ks = 0; ks < 64; ks += 32) {
      bf16x8_t afrag = *(const bf16x8_t*)(muRow + k0 + ks + quad * 8);
#pragma unroll
      for (int nt = 0; nt < 7; ++nt) {
        const ushort* bb = &bT[(nt * 16 + n) * 68 + ks + quad * 8];
        bf16x4_t lo = *(const bf16x4_t*)(bb);
        bf16x4_t hi = *(const bf16x4_t*)(bb + 4);
        bf16x8_t bfrag;
#pragma unroll
        for (int j = 0; j < 4; ++j) { bfrag[j] = lo[j]; bfrag[4 + j] = hi[j]; }
        acc[nt] = __builtin_amdgcn_mfma_f32_16x16x32_bf16(afrag, bfrag, acc[nt], 0, 0, 0);
      }
    }
  }
  // C/D layout: col = lane&15, row = quad*4 + reg
#pragma unroll
  for (int nt = 0; nt < 7; ++nt) {
    int c = nt * 16 + n;
    if (c < C_) {
#pragma unroll
      for (int r = 0; r < 4; ++r) {
        int m = m0 + wave * 16 + quad * 4 + r;
        part[((size_t)t * B_ + m) * C_ + c] = acc[nt][r];
      }
    }
  }
}

// ---------------------------------------------------------------------------
// k6: out[b][c] = log( (sum_t part[t][b][c]) / (L*T) )
// ---------------------------------------------------------------------------
__global__ __launch_bounds__(256) void k6_log(
    const float* __restrict__ part, float* __restrict__ out) {
  int i = blockIdx.x * 256 + threadIdx.x;
  if (i < B_ * C_) {
    float s = 0.0f;
#pragma unroll
    for (int t = 0; t < T_; ++t) s += part[(size_t)t * B_ * C_ + i];
    out[i] = logf(s * (1.0f / (L_ * T_)));
  }
}

extern "C" void kernel_launch(void* const* d_in, const int* in_sizes, int n_in,
                              void* d_out, int out_size, void* d_ws,
                              size_t ws_size, hipStream_t stream) {
  const float* feat = (const float*)d_in[0];
  const float* W1   = (const float*)d_in[1];
  const float* b1   = (const float*)d_in[2];
  const float* W2   = (const float*)d_in[3];
  const float* b2   = (const float*)d_in[4];
  const float* pi   = (const float*)d_in[5];
  float* out = (float*)d_out;

  char* ws = (char*)d_ws;
  float*           h_buf    = (float*)(ws);                                 // 8 MB
  __hip_bfloat16*  mu_buf   = (__hip_bfloat16*)(ws + ((size_t)8  << 20));   // 16 MB
  __hip_bfloat16*  leaf_buf = (__hip_bfloat16*)(ws + ((size_t)24 << 20));   // 1.75 MB
  float*           part_buf = (float*)(ws + ((size_t)26 << 20));            // 6.55 MB

  k1_gemm_h<<<dim3(B_ / 32, T_), 256, 0, stream>>>(feat, W1, b1, h_buf);
  k2_p_mu<<<dim3(B_ / 8, T_), 256, 0, stream>>>(h_buf, W2, b2, mu_buf);
  k4_softmax<<<(T_ * L_) / 4, 256, 0, stream>>>(pi, leaf_buf);
  k5_mfma<<<dim3(B_ / 64, T_), 256, 0, stream>>>(
      (const ushort*)mu_buf, (const ushort*)leaf_buf, part_buf);
  k6_log<<<(B_ * C_ + 255) / 256, 256, 0, stream>>>(part_buf, out);
}

// Round 5
// 120.885 us; speedup vs baseline: 2.6820x; 1.5657x over previous
//
#include <hip/hip_runtime.h>
#include <hip/hip_bf16.h>
#include <math.h>

#define T_ 16
#define B_ 1024
#define F_ 512
#define H_ 128
#define D_ 8
#define C_ 100
#define L_ 512
#define CP_ 112   // C padded to multiple of 16 for MFMA N

typedef __attribute__((ext_vector_type(8))) short bf16x8_t;
typedef __attribute__((ext_vector_type(4))) short bf16x4_t;
typedef __attribute__((ext_vector_type(4))) float f32x4_t;

__device__ inline ushort f2bf(float x) {
  __hip_bfloat16 b = __float2bfloat16(x);
  return *(ushort*)&b;
}
__device__ inline float bf2f(ushort u) {
  union { unsigned int i; float f; } v;
  v.i = ((unsigned int)u) << 16;
  return v.f;
}

// ---------------------------------------------------------------------------
// k0_cvt: fp32 -> bf16 elementwise (feat). n must be multiple of 8*256.
// ---------------------------------------------------------------------------
__global__ __launch_bounds__(256) void k0_cvt(
    const float* __restrict__ X, ushort* __restrict__ Y) {
  int i = (blockIdx.x * 256 + threadIdx.x) * 8;
  float4 a = *(const float4*)(X + i);
  float4 b = *(const float4*)(X + i + 4);
  bf16x8_t o;
  o[0] = (short)f2bf(a.x); o[1] = (short)f2bf(a.y);
  o[2] = (short)f2bf(a.z); o[3] = (short)f2bf(a.w);
  o[4] = (short)f2bf(b.x); o[5] = (short)f2bf(b.y);
  o[6] = (short)f2bf(b.z); o[7] = (short)f2bf(b.w);
  *(bf16x8_t*)(Y + i) = o;
}

// ---------------------------------------------------------------------------
// k0_transpose: X[s][K][N] fp32 -> XT[s][N][K] bf16.  grid (K/32, N/32, S)
// ---------------------------------------------------------------------------
__global__ __launch_bounds__(256) void k0_transpose(
    const float* __restrict__ X, ushort* __restrict__ XT, int K, int N) {
  __shared__ float tile[32][33];
  const int k0 = blockIdx.x * 32, n0 = blockIdx.y * 32, s = blockIdx.z;
  const int c = threadIdx.x & 31, r0 = threadIdx.x >> 5;
  const float* Xs = X + (size_t)s * K * N;
  ushort* XTs = XT + (size_t)s * N * K;
#pragma unroll
  for (int j = 0; j < 4; ++j)
    tile[r0 + 8 * j][c] = Xs[(size_t)(k0 + r0 + 8 * j) * N + n0 + c];
  __syncthreads();
#pragma unroll
  for (int j = 0; j < 4; ++j)
    XTs[(size_t)(n0 + r0 + 8 * j) * K + k0 + c] = f2bf(tile[c][r0 + 8 * j]);
}

// ---------------------------------------------------------------------------
// k1: h[t][b][j] = relu(feat @ W1[t] + b1[t]) via bf16 MFMA, bf16 out.
// grid (B/32=32, T), 256 thr (4 waves). Block tile M=32, N=128, K=512.
// ---------------------------------------------------------------------------
__global__ __launch_bounds__(256) void k1_mfma(
    const ushort* __restrict__ feat, const ushort* __restrict__ W1T,
    const float* __restrict__ b1, ushort* __restrict__ h_out) {
  __shared__ ushort a_s[32][72];    // row pitch 144 B (x16 -> aligned b128)
  __shared__ ushort b_s[128][72];
  const int t = blockIdx.y, b0 = blockIdx.x * 32, tid = threadIdx.x;
  const int w = tid >> 6, lane = tid & 63, quad = lane >> 4, n = lane & 15;

  f32x4_t acc[2][2];
#pragma unroll
  for (int i = 0; i < 2; ++i)
#pragma unroll
    for (int j = 0; j < 2; ++j) acc[i][j] = (f32x4_t){0.f, 0.f, 0.f, 0.f};

  for (int kc = 0; kc < 8; ++kc) {
    __syncthreads();
    {
      int row = tid >> 3, col8 = (tid & 7) * 8;
      *(bf16x8_t*)&a_s[row][col8] =
          *(const bf16x8_t*)(feat + (size_t)(b0 + row) * F_ + kc * 64 + col8);
    }
#pragma unroll
    for (int i = 0; i < 4; ++i) {
      int idx = i * 256 + tid;
      int row = idx >> 3, col8 = (idx & 7) * 8;
      *(bf16x8_t*)&b_s[row][col8] =
          *(const bf16x8_t*)(W1T + ((size_t)t * H_ + row) * F_ + kc * 64 + col8);
    }
    __syncthreads();
#pragma unroll
    for (int ks = 0; ks < 64; ks += 32) {
      bf16x8_t af[2], bf[2];
#pragma unroll
      for (int mt = 0; mt < 2; ++mt)
        af[mt] = *(const bf16x8_t*)&a_s[mt * 16 + n][ks + quad * 8];
#pragma unroll
      for (int nt = 0; nt < 2; ++nt)
        bf[nt] = *(const bf16x8_t*)&b_s[w * 32 + nt * 16 + n][ks + quad * 8];
#pragma unroll
      for (int mt = 0; mt < 2; ++mt)
#pragma unroll
        for (int nt = 0; nt < 2; ++nt)
          acc[mt][nt] = __builtin_amdgcn_mfma_f32_16x16x32_bf16(
              af[mt], bf[nt], acc[mt][nt], 0, 0, 0);
    }
  }
  float bias[2] = {b1[t * H_ + w * 32 + n], b1[t * H_ + w * 32 + 16 + n]};
#pragma unroll
  for (int mt = 0; mt < 2; ++mt)
#pragma unroll
    for (int nt = 0; nt < 2; ++nt)
#pragma unroll
      for (int r = 0; r < 4; ++r) {
        int row = b0 + mt * 16 + quad * 4 + r;
        int col = w * 32 + nt * 16 + n;
        float v = acc[mt][nt][r] + bias[nt];
        h_out[((size_t)t * B_ + row) * H_ + col] = f2bf(v > 0.f ? v : 0.f);
      }
}

// ---------------------------------------------------------------------------
// k2: x = h @ W2[t] + b2 (MFMA), p = sigmoid(x) -> LDS bf16, then tree-
// factored routing product -> mu bf16.
// grid (B/32=32, T), 256 thr. M=32, N=512 (8 chunks of 64), K=128. LDS 59.4 KB
// ---------------------------------------------------------------------------
__global__ __launch_bounds__(256) void k2_mfma(
    const ushort* __restrict__ h, const ushort* __restrict__ W2T,
    const float* __restrict__ b2, ushort* __restrict__ mu) {
  __shared__ ushort h_s[32][136];   // pitch 272 B (x16)
  __shared__ ushort w_s[64][136];
  __shared__ ushort p_s[32][520];
  const int t = blockIdx.y, b0 = blockIdx.x * 32, tid = threadIdx.x;
  const int w = tid >> 6, lane = tid & 63, quad = lane >> 4, n = lane & 15;

#pragma unroll
  for (int i = 0; i < 2; ++i) {
    int idx = i * 256 + tid;                 // 512 vec loads: 32 x 128
    int row = idx >> 4, col8 = (idx & 15) * 8;
    *(bf16x8_t*)&h_s[row][col8] =
        *(const bf16x8_t*)(h + ((size_t)t * B_ + b0 + row) * H_ + col8);
  }

  for (int nc = 0; nc < 8; ++nc) {
    __syncthreads();
#pragma unroll
    for (int i = 0; i < 4; ++i) {
      int idx = i * 256 + tid;               // 1024 vec loads: 64 x 128
      int row = idx >> 4, col8 = (idx & 15) * 8;
      *(bf16x8_t*)&w_s[row][col8] =
          *(const bf16x8_t*)(W2T + ((size_t)t * L_ + nc * 64 + row) * H_ + col8);
    }
    __syncthreads();
    f32x4_t acc[2];
    acc[0] = (f32x4_t){0.f, 0.f, 0.f, 0.f};
    acc[1] = (f32x4_t){0.f, 0.f, 0.f, 0.f};
#pragma unroll
    for (int ks = 0; ks < 128; ks += 32) {
      bf16x8_t bfrag = *(const bf16x8_t*)&w_s[w * 16 + n][ks + quad * 8];
#pragma unroll
      for (int mt = 0; mt < 2; ++mt) {
        bf16x8_t afrag = *(const bf16x8_t*)&h_s[mt * 16 + n][ks + quad * 8];
        acc[mt] = __builtin_amdgcn_mfma_f32_16x16x32_bf16(afrag, bfrag,
                                                          acc[mt], 0, 0, 0);
      }
    }
    int l = nc * 64 + w * 16 + n;
    float bias = b2[t * L_ + l];
#pragma unroll
    for (int mt = 0; mt < 2; ++mt)
#pragma unroll
      for (int r = 0; r < 4; ++r) {
        float x = acc[mt][r] + bias;
        p_s[mt * 16 + quad * 4 + r][l] = f2bf(1.0f / (1.0f + __expf(-x)));
      }
  }
  __syncthreads();

  // routing: thread handles (row b, 16-leaf subtree s); leaf l = s*16 + i.
#pragma unroll
  for (int pass = 0; pass < 4; ++pass) {
    int b = pass * 8 + (tid >> 5);
    int s = tid & 31;
    float P = 1.f;
#pragma unroll
    for (int d = 0; d < 5; ++d) {
      int nd = (1 << d) - 1 + (s >> (5 - d));
      int sd = (s >> (4 - d)) & 1;
      float pv = bf2f(p_s[b][nd]);
      P *= sd ? (1.f - pv) : pv;
    }
    float p5 = bf2f(p_s[b][31 + s]);
    float q5[2] = {P * p5, P * (1.f - p5)};
    float q6[4], q7[8];
#pragma unroll
    for (int j = 0; j < 2; ++j) {
      float pv = bf2f(p_s[b][63 + 2 * s + j]);
      q6[2 * j] = q5[j] * pv;
      q6[2 * j + 1] = q5[j] * (1.f - pv);
    }
#pragma unroll
    for (int u = 0; u < 4; ++u) {
      float pv = bf2f(p_s[b][127 + 4 * s + u]);
      q7[2 * u] = q6[u] * pv;
      q7[2 * u + 1] = q6[u] * (1.f - pv);
    }
    bf16x8_t o0, o1;
#pragma unroll
    for (int v = 0; v < 8; ++v) {
      float pv = bf2f(p_s[b][255 + 8 * s + v]);
      ushort e0 = f2bf(q7[v] * pv);
      ushort e1 = f2bf(q7[v] * (1.f - pv));
      if (v < 4) { o0[2 * v] = (short)e0; o0[2 * v + 1] = (short)e1; }
      else       { o1[2 * (v - 4)] = (short)e0; o1[2 * (v - 4) + 1] = (short)e1; }
    }
    ushort* dst = mu + ((size_t)t * B_ + b0 + b) * L_ + s * 16;
    *(bf16x8_t*)dst = o0;
    *(bf16x8_t*)(dst + 8) = o1;
  }
}

// ---------------------------------------------------------------------------
// k4: leaf_p[t][l][:] = softmax(pi[t][l][:]) -> bf16, padded to CP_=112
// ---------------------------------------------------------------------------
__global__ __launch_bounds__(256) void k4_softmax(
    const float* __restrict__ pi, ushort* __restrict__ lp) {
  int row  = blockIdx.x * 4 + (threadIdx.x >> 6);
  int lane = threadIdx.x & 63;
  const float* x = pi + (size_t)row * C_;
  float v0 = (lane < C_) ? x[lane] : -1e30f;
  float v1 = (lane + 64 < C_) ? x[lane + 64] : -1e30f;
  float m = fmaxf(v0, v1);
#pragma unroll
  for (int off = 32; off; off >>= 1) m = fmaxf(m, __shfl_xor(m, off, 64));
  float e0 = __expf(v0 - m);
  float e1 = (lane + 64 < C_) ? __expf(v1 - m) : 0.0f;
  float s = e0 + e1;
#pragma unroll
  for (int off = 32; off; off >>= 1) s += __shfl_xor(s, off, 64);
  float inv = 1.0f / s;
  size_t base = (size_t)row * CP_;
  if (lane < C_) lp[base + lane] = f2bf(e0 * inv);
  int c2 = lane + 64;
  if (c2 < CP_) lp[base + c2] = f2bf(c2 < C_ ? e1 * inv : 0.0f);
}

// ---------------------------------------------------------------------------
// k5: MFMA mix: part[t][b][c] = sum_l mu[t][b][l] * lp[t][l][c]
// ---------------------------------------------------------------------------
__global__ __launch_bounds__(256) void k5_mfma(
    const ushort* __restrict__ mu, const ushort* __restrict__ lp,
    float* __restrict__ part) {
  __shared__ ushort bT[CP_ * 68];
  const int t   = blockIdx.y;
  const int m0  = blockIdx.x * 64;
  const int tid = threadIdx.x;
  const int wave = tid >> 6, lane = tid & 63;
  const int quad = lane >> 4;
  const int n    = lane & 15;
  const int mrow = m0 + wave * 16 + n;

  f32x4_t acc[7];
#pragma unroll
  for (int i = 0; i < 7; ++i) acc[i] = (f32x4_t){0.f, 0.f, 0.f, 0.f};

  const ushort* muRow = mu + ((size_t)t * B_ + mrow) * L_;
  const ushort* lp_t  = lp + (size_t)t * L_ * CP_;

  for (int k0 = 0; k0 < L_; k0 += 64) {
    __syncthreads();
#pragma unroll
    for (int i = 0; i < 28; ++i) {
      int e  = i * 256 + tid;
      int kk = e / CP_;
      int c  = e - kk * CP_;
      bT[c * 68 + kk] = lp_t[(size_t)(k0 + kk) * CP_ + c];
    }
    __syncthreads();
#pragma unroll
    for (int ks = 0; ks < 64; ks += 32) {
      bf16x8_t afrag = *(const bf16x8_t*)(muRow + k0 + ks + quad * 8);
#pragma unroll
      for (int nt = 0; nt < 7; ++nt) {
        const ushort* bb = &bT[(nt * 16 + n) * 68 + ks + quad * 8];
        bf16x4_t lo = *(const bf16x4_t*)(bb);
        bf16x4_t hi = *(const bf16x4_t*)(bb + 4);
        bf16x8_t bfrag;
#pragma unroll
        for (int j = 0; j < 4; ++j) { bfrag[j] = lo[j]; bfrag[4 + j] = hi[j]; }
        acc[nt] = __builtin_amdgcn_mfma_f32_16x16x32_bf16(afrag, bfrag, acc[nt], 0, 0, 0);
      }
    }
  }
#pragma unroll
  for (int nt = 0; nt < 7; ++nt) {
    int c = nt * 16 + n;
    if (c < C_) {
#pragma unroll
      for (int r = 0; r < 4; ++r) {
        int m = m0 + wave * 16 + quad * 4 + r;
        part[((size_t)t * B_ + m) * C_ + c] = acc[nt][r];
      }
    }
  }
}

// ---------------------------------------------------------------------------
// k6: out[b][c] = log( (sum_t part[t][b][c]) / (L*T) )
// ---------------------------------------------------------------------------
__global__ __launch_bounds__(256) void k6_log(
    const float* __restrict__ part, float* __restrict__ out) {
  int i = blockIdx.x * 256 + threadIdx.x;
  if (i < B_ * C_) {
    float s = 0.0f;
#pragma unroll
    for (int t = 0; t < T_; ++t) s += part[(size_t)t * B_ * C_ + i];
    out[i] = logf(s * (1.0f / (L_ * T_)));
  }
}

extern "C" void kernel_launch(void* const* d_in, const int* in_sizes, int n_in,
                              void* d_out, int out_size, void* d_ws,
                              size_t ws_size, hipStream_t stream) {
  const float* feat = (const float*)d_in[0];
  const float* W1   = (const float*)d_in[1];
  const float* b1   = (const float*)d_in[2];
  const float* W2   = (const float*)d_in[3];
  const float* b2   = (const float*)d_in[4];
  const float* pi   = (const float*)d_in[5];
  float* out = (float*)d_out;

  char* ws = (char*)d_ws;
  // Disjoint regions only (no aliasing): total 33.25 MB.
  ushort* feat_bf  = (ushort*)(ws);                                // @0,  1 MB
  ushort* W1T_buf  = (ushort*)(ws + ((size_t)1 << 20));            // 2 MB
  ushort* W2T_buf  = (ushort*)(ws + ((size_t)3 << 20));            // 2 MB
  ushort* h_buf    = (ushort*)(ws + ((size_t)5 << 20));            // 4 MB
  ushort* mu_buf   = (ushort*)(ws + ((size_t)9 << 20));            // 16 MB
  ushort* leaf_buf = (ushort*)(ws + ((size_t)25 << 20));           // 1.75 MB
  float*  part_buf = (float*)(ws + ((size_t)27 << 20));            // 6.25 MB

  k0_cvt<<<(B_ * F_) / (256 * 8), 256, 0, stream>>>(feat, feat_bf);
  k0_transpose<<<dim3(F_ / 32, H_ / 32, T_), 256, 0, stream>>>(W1, W1T_buf, F_, H_);
  k0_transpose<<<dim3(H_ / 32, L_ / 32, T_), 256, 0, stream>>>(W2, W2T_buf, H_, L_);
  k4_softmax<<<(T_ * L_) / 4, 256, 0, stream>>>(pi, leaf_buf);
  k1_mfma<<<dim3(B_ / 32, T_), 256, 0, stream>>>(feat_bf, W1T_buf, b1, h_buf);
  k2_mfma<<<dim3(B_ / 32, T_), 256, 0, stream>>>(h_buf, W2T_buf, b2, mu_buf);
  k5_mfma<<<dim3(B_ / 64, T_), 256, 0, stream>>>(mu_buf, leaf_buf, part_buf);
  k6_log<<<(B_ * C_ + 255) / 256, 256, 0, stream>>>(part_buf, out);
}

// Round 6
// 114.538 us; speedup vs baseline: 2.8306x; 1.0554x over previous
//
#include <hip/hip_runtime.h>
#include <hip/hip_bf16.h>
#include <math.h>

#define T_ 16
#define B_ 1024
#define F_ 512
#define H_ 128
#define D_ 8
#define C_ 100
#define L_ 512
#define CP_ 112   // C padded to multiple of 16 for MFMA N

typedef __attribute__((ext_vector_type(8))) short bf16x8_t;
typedef __attribute__((ext_vector_type(4))) short bf16x4_t;
typedef __attribute__((ext_vector_type(4))) float f32x4_t;

__device__ inline ushort f2bf(float x) {
  __hip_bfloat16 b = __float2bfloat16(x);
  return *(ushort*)&b;
}
__device__ inline float bf2f(ushort u) {
  union { unsigned int i; float f; } v;
  v.i = ((unsigned int)u) << 16;
  return v.f;
}

// ---------------------------------------------------------------------------
// k_prep: fused independent preprocessing, block-range dispatch.
//   [0,256)      : feat fp32 -> bf16            (B*F/2048 blocks)
//   [256,1280)   : W1 [t][F][H] -> W1T [t][H][F] bf16
//   [1280,2304)  : W2 [t][H][L] -> W2T [t][L][H] bf16
//   [2304,4352)  : leaf_p = softmax(pi) -> bf16 padded CP_
// ---------------------------------------------------------------------------
__global__ __launch_bounds__(256) void k_prep(
    const float* __restrict__ feat, const float* __restrict__ W1,
    const float* __restrict__ W2, const float* __restrict__ pi,
    ushort* __restrict__ feat_bf, ushort* __restrict__ W1T,
    ushort* __restrict__ W2T, ushort* __restrict__ lp) {
  __shared__ float tile[32][33];
  const int bid = blockIdx.x, tid = threadIdx.x;

  if (bid < 256) {  // ---- feat cvt
    int i = (bid * 256 + tid) * 8;
    float4 a = *(const float4*)(feat + i);
    float4 b = *(const float4*)(feat + i + 4);
    bf16x8_t o;
    o[0] = (short)f2bf(a.x); o[1] = (short)f2bf(a.y);
    o[2] = (short)f2bf(a.z); o[3] = (short)f2bf(a.w);
    o[4] = (short)f2bf(b.x); o[5] = (short)f2bf(b.y);
    o[6] = (short)f2bf(b.z); o[7] = (short)f2bf(b.w);
    *(bf16x8_t*)(feat_bf + i) = o;
    return;
  }
  if (bid < 2304) {  // ---- transposes
    const float* X; ushort* XT; int K, N, kb, nb, s;
    if (bid < 1280) {
      int r = bid - 256;  kb = r & 15; nb = (r >> 4) & 3;  s = r >> 6;
      X = W1; XT = W1T; K = F_; N = H_;
    } else {
      int r = bid - 1280; kb = r & 3;  nb = (r >> 2) & 15; s = r >> 6;
      X = W2; XT = W2T; K = H_; N = L_;
    }
    const int k0 = kb * 32, n0 = nb * 32;
    const int c = tid & 31, r0 = tid >> 5;
    const float* Xs = X + (size_t)s * K * N;
    ushort* XTs = XT + (size_t)s * N * K;
#pragma unroll
    for (int j = 0; j < 4; ++j)
      tile[r0 + 8 * j][c] = Xs[(size_t)(k0 + r0 + 8 * j) * N + n0 + c];
    __syncthreads();
#pragma unroll
    for (int j = 0; j < 4; ++j)
      XTs[(size_t)(n0 + r0 + 8 * j) * K + k0 + c] = f2bf(tile[c][r0 + 8 * j]);
    return;
  }
  {  // ---- softmax rows
    int row  = (bid - 2304) * 4 + (tid >> 6);
    int lane = tid & 63;
    const float* x = pi + (size_t)row * C_;
    float v0 = (lane < C_) ? x[lane] : -1e30f;
    float v1 = (lane + 64 < C_) ? x[lane + 64] : -1e30f;
    float m = fmaxf(v0, v1);
#pragma unroll
    for (int off = 32; off; off >>= 1) m = fmaxf(m, __shfl_xor(m, off, 64));
    float e0 = __expf(v0 - m);
    float e1 = (lane + 64 < C_) ? __expf(v1 - m) : 0.0f;
    float sm = e0 + e1;
#pragma unroll
    for (int off = 32; off; off >>= 1) sm += __shfl_xor(sm, off, 64);
    float inv = 1.0f / sm;
    size_t base = (size_t)row * CP_;
    if (lane < C_) lp[base + lane] = f2bf(e0 * inv);
    int c2 = lane + 64;
    if (c2 < CP_) lp[base + c2] = f2bf(c2 < C_ ? e1 * inv : 0.0f);
  }
}

// ---------------------------------------------------------------------------
// k12: fused GEMM1 (h = relu(feat@W1+b1), kept in LDS) + GEMM2 + sigmoid +
// tree-factored routing -> mu bf16.  grid (B/32=32, T), 256 thr.
// LDS union 59392 B: h_s persists; phase-1 a_s/b_s alias phase-2 w_s/p_s.
// ---------------------------------------------------------------------------
__global__ __launch_bounds__(256) void k12_mfma(
    const ushort* __restrict__ feat, const ushort* __restrict__ W1T,
    const float* __restrict__ b1, const ushort* __restrict__ W2T,
    const float* __restrict__ b2, ushort* __restrict__ mu) {
  __shared__ ushort smem[29696];                        // 59392 B
  ushort (*h_s)[136] = (ushort(*)[136])smem;            // [32][136] @0
  ushort (*a_s)[72]  = (ushort(*)[72])(smem + 4352);    // [32][72]  ph1
  ushort (*b_s)[72]  = (ushort(*)[72])(smem + 6656);    // [128][72] ph1
  ushort (*w_s)[136] = (ushort(*)[136])(smem + 4352);   // [64][136] ph2
  ushort (*p_s)[520] = (ushort(*)[520])(smem + 13056);  // [32][520] ph2

  const int t = blockIdx.y, b0 = blockIdx.x * 32, tid = threadIdx.x;
  const int w = tid >> 6, lane = tid & 63, quad = lane >> 4, n = lane & 15;

  // ---------------- phase 1: h tile (M=32, N=128, K=512) ----------------
  {
    f32x4_t acc[2][2];
#pragma unroll
    for (int i = 0; i < 2; ++i)
#pragma unroll
      for (int j = 0; j < 2; ++j) acc[i][j] = (f32x4_t){0.f, 0.f, 0.f, 0.f};

    for (int kc = 0; kc < 8; ++kc) {
      __syncthreads();
      {
        int row = tid >> 3, col8 = (tid & 7) * 8;
        *(bf16x8_t*)&a_s[row][col8] =
            *(const bf16x8_t*)(feat + (size_t)(b0 + row) * F_ + kc * 64 + col8);
      }
#pragma unroll
      for (int i = 0; i < 4; ++i) {
        int idx = i * 256 + tid;
        int row = idx >> 3, col8 = (idx & 7) * 8;
        *(bf16x8_t*)&b_s[row][col8] =
            *(const bf16x8_t*)(W1T + ((size_t)t * H_ + row) * F_ + kc * 64 + col8);
      }
      __syncthreads();
#pragma unroll
      for (int ks = 0; ks < 64; ks += 32) {
        bf16x8_t af[2], bfr[2];
#pragma unroll
        for (int mt = 0; mt < 2; ++mt)
          af[mt] = *(const bf16x8_t*)&a_s[mt * 16 + n][ks + quad * 8];
#pragma unroll
        for (int nt = 0; nt < 2; ++nt)
          bfr[nt] = *(const bf16x8_t*)&b_s[w * 32 + nt * 16 + n][ks + quad * 8];
#pragma unroll
        for (int mt = 0; mt < 2; ++mt)
#pragma unroll
          for (int nt = 0; nt < 2; ++nt)
            acc[mt][nt] = __builtin_amdgcn_mfma_f32_16x16x32_bf16(
                af[mt], bfr[nt], acc[mt][nt], 0, 0, 0);
      }
    }
    float bias[2] = {b1[t * H_ + w * 32 + n], b1[t * H_ + w * 32 + 16 + n]};
#pragma unroll
    for (int mt = 0; mt < 2; ++mt)
#pragma unroll
      for (int nt = 0; nt < 2; ++nt)
#pragma unroll
        for (int r = 0; r < 4; ++r) {
          int row = mt * 16 + quad * 4 + r;
          int col = w * 32 + nt * 16 + n;
          float v = acc[mt][nt][r] + bias[nt];
          h_s[row][col] = f2bf(v > 0.f ? v : 0.f);   // h_s region: no hazard
        }
  }

  // ---------------- phase 2: GEMM2 + sigmoid -> p_s ----------------
  for (int nc = 0; nc < 8; ++nc) {
    __syncthreads();   // h_s writes done; w_s clobbers a_s/b_s safely
#pragma unroll
    for (int i = 0; i < 4; ++i) {
      int idx = i * 256 + tid;
      int row = idx >> 4, col8 = (idx & 15) * 8;
      *(bf16x8_t*)&w_s[row][col8] =
          *(const bf16x8_t*)(W2T + ((size_t)t * L_ + nc * 64 + row) * H_ + col8);
    }
    __syncthreads();
    f32x4_t acc[2];
    acc[0] = (f32x4_t){0.f, 0.f, 0.f, 0.f};
    acc[1] = (f32x4_t){0.f, 0.f, 0.f, 0.f};
#pragma unroll
    for (int ks = 0; ks < 128; ks += 32) {
      bf16x8_t bfrag = *(const bf16x8_t*)&w_s[w * 16 + n][ks + quad * 8];
#pragma unroll
      for (int mt = 0; mt < 2; ++mt) {
        bf16x8_t afrag = *(const bf16x8_t*)&h_s[mt * 16 + n][ks + quad * 8];
        acc[mt] = __builtin_amdgcn_mfma_f32_16x16x32_bf16(afrag, bfrag,
                                                          acc[mt], 0, 0, 0);
      }
    }
    int l = nc * 64 + w * 16 + n;
    float bias = b2[t * L_ + l];
#pragma unroll
    for (int mt = 0; mt < 2; ++mt)
#pragma unroll
      for (int r = 0; r < 4; ++r) {
        float x = acc[mt][r] + bias;
        p_s[mt * 16 + quad * 4 + r][l] = f2bf(1.0f / (1.0f + __expf(-x)));
      }
  }
  __syncthreads();

  // ---------------- routing: (row b, 16-leaf subtree s) ----------------
#pragma unroll
  for (int pass = 0; pass < 4; ++pass) {
    int b = pass * 8 + (tid >> 5);
    int s = tid & 31;
    float P = 1.f;
#pragma unroll
    for (int d = 0; d < 5; ++d) {
      int nd = (1 << d) - 1 + (s >> (5 - d));
      int sd = (s >> (4 - d)) & 1;
      float pv = bf2f(p_s[b][nd]);
      P *= sd ? (1.f - pv) : pv;
    }
    float p5 = bf2f(p_s[b][31 + s]);
    float q5[2] = {P * p5, P * (1.f - p5)};
    float q6[4], q7[8];
#pragma unroll
    for (int j = 0; j < 2; ++j) {
      float pv = bf2f(p_s[b][63 + 2 * s + j]);
      q6[2 * j] = q5[j] * pv;
      q6[2 * j + 1] = q5[j] * (1.f - pv);
    }
#pragma unroll
    for (int u = 0; u < 4; ++u) {
      float pv = bf2f(p_s[b][127 + 4 * s + u]);
      q7[2 * u] = q6[u] * pv;
      q7[2 * u + 1] = q6[u] * (1.f - pv);
    }
    bf16x8_t o0, o1;
#pragma unroll
    for (int v = 0; v < 8; ++v) {
      float pv = bf2f(p_s[b][255 + 8 * s + v]);
      ushort e0 = f2bf(q7[v] * pv);
      ushort e1 = f2bf(q7[v] * (1.f - pv));
      if (v < 4) { o0[2 * v] = (short)e0; o0[2 * v + 1] = (short)e1; }
      else       { o1[2 * (v - 4)] = (short)e0; o1[2 * (v - 4) + 1] = (short)e1; }
    }
    ushort* dst = mu + ((size_t)t * B_ + b0 + b) * L_ + s * 16;
    *(bf16x8_t*)dst = o0;
    *(bf16x8_t*)(dst + 8) = o1;
  }
}

// ---------------------------------------------------------------------------
// k5: MFMA mix: part[t][b][c] = sum_l mu[t][b][l] * lp[t][l][c]  (verified)
// ---------------------------------------------------------------------------
__global__ __launch_bounds__(256) void k5_mfma(
    const ushort* __restrict__ mu, const ushort* __restrict__ lp,
    float* __restrict__ part) {
  __shared__ ushort bT[CP_ * 68];
  const int t   = blockIdx.y;
  const int m0  = blockIdx.x * 64;
  const int tid = threadIdx.x;
  const int wave = tid >> 6, lane = tid & 63;
  const int quad = lane >> 4;
  const int n    = lane & 15;
  const int mrow = m0 + wave * 16 + n;

  f32x4_t acc[7];
#pragma unroll
  for (int i = 0; i < 7; ++i) acc[i] = (f32x4_t){0.f, 0.f, 0.f, 0.f};

  const ushort* muRow = mu + ((size_t)t * B_ + mrow) * L_;
  const ushort* lp_t  = lp + (size_t)t * L_ * CP_;

  for (int k0 = 0; k0 < L_; k0 += 64) {
    __syncthreads();
#pragma unroll
    for (int i = 0; i < 28; ++i) {
      int e  = i * 256 + tid;
      int kk = e / CP_;
      int c  = e - kk * CP_;
      bT[c * 68 + kk] = lp_t[(size_t)(k0 + kk) * CP_ + c];
    }
    __syncthreads();
#pragma unroll
    for (int ks = 0; ks < 64; ks += 32) {
      bf16x8_t afrag = *(const bf16x8_t*)(muRow + k0 + ks + quad * 8);
#pragma unroll
      for (int nt = 0; nt < 7; ++nt) {
        const ushort* bb = &bT[(nt * 16 + n) * 68 + ks + quad * 8];
        bf16x4_t lo = *(const bf16x4_t*)(bb);
        bf16x4_t hi = *(const bf16x4_t*)(bb + 4);
        bf16x8_t bfrag;
#pragma unroll
        for (int j = 0; j < 4; ++j) { bfrag[j] = lo[j]; bfrag[4 + j] = hi[j]; }
        acc[nt] = __builtin_amdgcn_mfma_f32_16x16x32_bf16(afrag, bfrag, acc[nt], 0, 0, 0);
      }
    }
  }
#pragma unroll
  for (int nt = 0; nt < 7; ++nt) {
    int c = nt * 16 + n;
    if (c < C_) {
#pragma unroll
      for (int r = 0; r < 4; ++r) {
        int m = m0 + wave * 16 + quad * 4 + r;
        part[((size_t)t * B_ + m) * C_ + c] = acc[nt][r];
      }
    }
  }
}

// ---------------------------------------------------------------------------
// k6: out[b][c] = log( (sum_t part[t][b][c]) / (L*T) )
// ---------------------------------------------------------------------------
__global__ __launch_bounds__(256) void k6_log(
    const float* __restrict__ part, float* __restrict__ out) {
  int i = blockIdx.x * 256 + threadIdx.x;
  if (i < B_ * C_) {
    float s = 0.0f;
#pragma unroll
    for (int t = 0; t < T_; ++t) s += part[(size_t)t * B_ * C_ + i];
    out[i] = logf(s * (1.0f / (L_ * T_)));
  }
}

extern "C" void kernel_launch(void* const* d_in, const int* in_sizes, int n_in,
                              void* d_out, int out_size, void* d_ws,
                              size_t ws_size, hipStream_t stream) {
  const float* feat = (const float*)d_in[0];
  const float* W1   = (const float*)d_in[1];
  const float* b1   = (const float*)d_in[2];
  const float* W2   = (const float*)d_in[3];
  const float* b2   = (const float*)d_in[4];
  const float* pi   = (const float*)d_in[5];
  float* out = (float*)d_out;

  char* ws = (char*)d_ws;
  // Disjoint regions, no aliasing: total 29.25 MB.
  ushort* feat_bf  = (ushort*)(ws);                                // 1 MB
  ushort* W1T_buf  = (ushort*)(ws + ((size_t)1 << 20));            // 2 MB
  ushort* W2T_buf  = (ushort*)(ws + ((size_t)3 << 20));            // 2 MB
  ushort* mu_buf   = (ushort*)(ws + ((size_t)5 << 20));            // 16 MB
  ushort* leaf_buf = (ushort*)(ws + ((size_t)21 << 20));           // 1.75 MB
  float*  part_buf = (float*)(ws + ((size_t)23 << 20));            // 6.25 MB

  k_prep<<<4352, 256, 0, stream>>>(feat, W1, W2, pi, feat_bf, W1T_buf,
                                   W2T_buf, leaf_buf);
  k12_mfma<<<dim3(B_ / 32, T_), 256, 0, stream>>>(feat_bf, W1T_buf, b1,
                                                  W2T_buf, b2, mu_buf);
  k5_mfma<<<dim3(B_ / 64, T_), 256, 0, stream>>>(mu_buf, leaf_buf, part_buf);
  k6_log<<<(B_ * C_ + 255) / 256, 256, 0, stream>>>(part_buf, out);
}